// Round 6
// baseline (77.038 us; speedup 1.0000x reference)
//
#include <hip/hip_runtime.h>
#include <hip/hip_bf16.h>
#include <math.h>

// Problem constants (from reference)
#define V_SZ 500000
#define E_SZ 128
#define H_SZ 128
#define L_SZ 10
#define P_SZ 10
#define N_SZ 50
#define B_SZ (1 + P_SZ + N_SZ)   // 61 sequences
#define G_SZ (3 * H_SZ)          // 384 gate outputs

__device__ __forceinline__ float sigmoidf(float x) {
    return 1.0f / (1.0f + expf(-x));
}

// One block per sequence. 384 threads: thread t owns gate output g = t.
__global__ __launch_bounds__(G_SZ) void gru_encode(
    const int*   __restrict__ phr_inds,   // [L]
    const int*   __restrict__ pos_inds,   // [P][L]
    const int*   __restrict__ neg_inds,   // [N][L]
    const float* __restrict__ u_emb,      // [V][E]
    const float* __restrict__ v_emb,      // [V][E]
    const float* __restrict__ w_ih,       // [3H][E]
    const float* __restrict__ w_hh,       // [3H][H]
    const float* __restrict__ b_ih,       // [3H]
    const float* __restrict__ b_hh,       // [3H]
    const float* __restrict__ h0,         // [H]
    float*       __restrict__ enc)        // [B][H] (workspace)
{
    __shared__ float xs[L_SZ][E_SZ];   // gathered input rows
    __shared__ float hs[H_SZ];         // hidden state
    __shared__ float gi_s[G_SZ];       // gi_t + b_ih
    __shared__ float gh_s[G_SZ];       // gh + b_hh

    const int b = blockIdx.x;
    const int t = threadIdx.x;

    // ---- gather x = emb[idx] into LDS (320 float4 loads) ----
    const float* emb = (b == 0) ? u_emb : v_emb;
    if (t < L_SZ * (E_SZ / 4)) {
        const int l  = t / (E_SZ / 4);
        const int e4 = t % (E_SZ / 4);
        int idx;
        if (b == 0)            idx = phr_inds[l];
        else if (b <= P_SZ)    idx = pos_inds[(b - 1) * L_SZ + l];
        else                   idx = neg_inds[(b - 1 - P_SZ) * L_SZ + l];
        reinterpret_cast<float4*>(&xs[l][0])[e4] =
            reinterpret_cast<const float4*>(emb + (size_t)idx * E_SZ)[e4];
    }
    if (t < H_SZ) hs[t] = h0[t];
    __syncthreads();

    // ---- precompute gi[l] = x[l] . w_ih[g]  (w row loaded once, used 10x) ----
    const int g = t;
    float gi[L_SZ];
    #pragma unroll
    for (int l = 0; l < L_SZ; ++l) gi[l] = 0.0f;

    const float4* wih4 = reinterpret_cast<const float4*>(w_ih + (size_t)g * E_SZ);
    #pragma unroll 4
    for (int e4 = 0; e4 < E_SZ / 4; ++e4) {
        const float4 w = wih4[e4];
        #pragma unroll
        for (int l = 0; l < L_SZ; ++l) {
            const float4 xv = reinterpret_cast<const float4*>(&xs[l][0])[e4];
            gi[l] += w.x * xv.x + w.y * xv.y + w.z * xv.z + w.w * xv.w;
        }
    }
    const float bih = b_ih[g];
    const float bhh = b_hh[g];
    const float4* whh4 = reinterpret_cast<const float4*>(w_hh + (size_t)g * H_SZ);

    // ---- recurrent steps ----
    float hnew = 0.0f;
    for (int l = 0; l < L_SZ; ++l) {
        // gh[g] = h . w_hh[g] + b_hh[g]   (hs reads are wave-broadcast: conflict-free)
        float gh = bhh;
        #pragma unroll 8
        for (int j4 = 0; j4 < H_SZ / 4; ++j4) {
            const float4 w  = whh4[j4];
            const float4 hv = reinterpret_cast<const float4*>(hs)[j4];
            gh += w.x * hv.x + w.y * hv.y + w.z * hv.z + w.w * hv.w;
        }
        gi_s[g] = gi[l] + bih;
        gh_s[g] = gh;
        __syncthreads();                       // [A] gates visible

        if (t < H_SZ) {
            const float r = sigmoidf(gi_s[t]           + gh_s[t]);
            const float z = sigmoidf(gi_s[t + H_SZ]    + gh_s[t + H_SZ]);
            const float n = tanhf  (gi_s[t + 2*H_SZ] + r * gh_s[t + 2*H_SZ]);
            hnew = (1.0f - z) * n + z * hs[t];
        }
        __syncthreads();                       // [B] all hs reads done
        if (t < H_SZ) hs[t] = hnew;
        __syncthreads();                       // [C] new hs visible
    }

    if (t < H_SZ) enc[(size_t)b * H_SZ + t] = hnew;
}

// Single wave: lane j handles enc row 1+j (10 pos + 50 neg = 60 rows)
__global__ __launch_bounds__(64) void loss_kernel(
    const float* __restrict__ enc,   // [B][H]
    float* __restrict__ out)         // f32 scalar — reference output dtype is float32
{
    __shared__ float node[H_SZ];
    const int t = threadIdx.x;
    node[t]      = enc[t];
    node[t + 64] = enc[t + 64];
    __syncthreads();

    float vp = 0.0f, vn = 0.0f;
    if (t < P_SZ + N_SZ) {
        const float4* row4 = reinterpret_cast<const float4*>(enc + (size_t)(1 + t) * H_SZ);
        float s = 0.0f;
        #pragma unroll 8
        for (int i4 = 0; i4 < H_SZ / 4; ++i4) {
            const float4 r = row4[i4];
            const float4 n = reinterpret_cast<const float4*>(node)[i4];
            s += n.x * r.x + n.y * r.y + n.z * r.z + n.w * r.w;
        }
        s *= (1.0f / (float)H_SZ);
        if (t < P_SZ) vp = s;                               // pos dot
        else          vn = (s > 0.0f) ? expf(s) : 0.0f;     // exp(s)*(s>0)
    }

    // 64-lane butterfly reduce
    #pragma unroll
    for (int off = 32; off > 0; off >>= 1) {
        vp += __shfl_down(vp, off);
        vn += __shfl_down(vn, off);
    }
    if (t == 0) {
        const float loss = logf(1.0f + vn) - vp;   // -(neg_loss + pos_loss)
        out[0] = loss;                              // f32 write (was the round-0 bug: bf16)
    }
}

extern "C" void kernel_launch(void* const* d_in, const int* in_sizes, int n_in,
                              void* d_out, int out_size, void* d_ws, size_t ws_size,
                              hipStream_t stream) {
    const int*   phr_inds = (const int*)  d_in[0];
    const int*   pos_inds = (const int*)  d_in[1];
    const int*   neg_inds = (const int*)  d_in[2];
    const float* u_emb    = (const float*)d_in[3];
    const float* v_emb    = (const float*)d_in[4];
    const float* w_ih     = (const float*)d_in[5];
    const float* w_hh     = (const float*)d_in[6];
    const float* b_ih     = (const float*)d_in[7];
    const float* b_hh     = (const float*)d_in[8];
    const float* h0       = (const float*)d_in[9];

    float* enc = (float*)d_ws;   // [B][H] = 61*128 floats

    gru_encode<<<B_SZ, G_SZ, 0, stream>>>(phr_inds, pos_inds, neg_inds,
                                          u_emb, v_emb, w_ih, w_hh, b_ih, b_hh, h0,
                                          enc);
    loss_kernel<<<1, 64, 0, stream>>>(enc, (float*)d_out);
}

// Round 7
// 42.693 us; speedup vs baseline: 1.8044x; 1.8044x over previous
//
#include <hip/hip_runtime.h>
#include <hip/hip_bf16.h>
#include <math.h>

// Problem constants (from reference)
#define V_SZ 500000
#define E_SZ 128
#define H_SZ 128
#define L_SZ 10
#define P_SZ 10
#define N_SZ 50
#define B_SZ (1 + P_SZ + N_SZ)   // 61 sequences
#define G_SZ (3 * H_SZ)          // 384 gate outputs

__device__ __forceinline__ float sigmoidf(float x) {
    return 1.0f / (1.0f + expf(-x));
}

__device__ __forceinline__ float dot4(const float4 a, const float4 b) {
    return a.x * b.x + a.y * b.y + a.z * b.z + a.w * b.w;
}

// One block per sequence. 384 threads: thread t owns gate row g = t.
// w_ih/w_hh rows live in registers (float4 wreg[32], fully unrolled).
__global__ __launch_bounds__(G_SZ) void gru_encode(
    const int*   __restrict__ phr_inds,   // [L]
    const int*   __restrict__ pos_inds,   // [P][L]
    const int*   __restrict__ neg_inds,   // [N][L]
    const float* __restrict__ u_emb,      // [V][E]
    const float* __restrict__ v_emb,      // [V][E]
    const float* __restrict__ w_ih,       // [3H][E]
    const float* __restrict__ w_hh,       // [3H][H]
    const float* __restrict__ b_ih,       // [3H]
    const float* __restrict__ b_hh,       // [3H]
    const float* __restrict__ h0,         // [H]
    float*       __restrict__ enc)        // [B][H] (workspace)
{
    __shared__ float xs[L_SZ][E_SZ];       // gathered input rows (5 KB)
    __shared__ float gi_all[L_SZ][G_SZ];   // gi + b_ih for ALL steps (15 KB)
    __shared__ float hs[2][H_SZ];          // double-buffered hidden state
    __shared__ float gh_s[G_SZ];           // gh exchange

    const int b = blockIdx.x;
    const int t = threadIdx.x;

    // ---- gather x = emb[idx] into LDS (320 float4 loads) ----
    if (t < L_SZ * (E_SZ / 4)) {
        const float* emb = (b == 0) ? u_emb : v_emb;
        const int l  = t / (E_SZ / 4);
        const int e4 = t % (E_SZ / 4);
        int idx;
        if (b == 0)            idx = phr_inds[l];
        else if (b <= P_SZ)    idx = pos_inds[(b - 1) * L_SZ + l];
        else                   idx = neg_inds[(b - 1 - P_SZ) * L_SZ + l];
        reinterpret_cast<float4*>(&xs[l][0])[e4] =
            reinterpret_cast<const float4*>(emb + (size_t)idx * E_SZ)[e4];
    }
    if (t < H_SZ) hs[0][t] = h0[t];

    const float bih = b_ih[t];
    const float bhh = b_hh[t];

    // ---- load w_ih row into registers while the gather lands ----
    float4 wreg[E_SZ / 4];                 // 128 VGPRs, static indexing only
    {
        const float4* wih4 = reinterpret_cast<const float4*>(w_ih + (size_t)t * E_SZ);
        #pragma unroll
        for (int j = 0; j < E_SZ / 4; ++j) wreg[j] = wih4[j];
    }
    __syncthreads();   // xs, hs[0] visible

    // ---- gi[l][g] = x[l] . w_ih[g] + b_ih[g], all 10 steps at once ----
    {
        float gacc[L_SZ];
        #pragma unroll
        for (int l = 0; l < L_SZ; ++l) gacc[l] = 0.0f;

        #pragma unroll
        for (int j = 0; j < E_SZ / 4; ++j) {
            const float4 w = wreg[j];
            #pragma unroll
            for (int l = 0; l < L_SZ; ++l) {
                const float4 xv = reinterpret_cast<const float4*>(&xs[l][0])[j];  // broadcast
                gacc[l] += dot4(w, xv);
            }
        }
        #pragma unroll
        for (int l = 0; l < L_SZ; ++l) gi_all[l][t] = gacc[l] + bih;
    }

    // ---- swap register weights to the w_hh row ----
    {
        const float4* whh4 = reinterpret_cast<const float4*>(w_hh + (size_t)t * H_SZ);
        #pragma unroll
        for (int j = 0; j < H_SZ / 4; ++j) wreg[j] = whh4[j];
    }
    __syncthreads();   // gi_all visible

    // ---- recurrent steps: 2 barriers/step, zero global loads ----
    int cur = 0;
    float hnew = 0.0f;
    for (int l = 0; l < L_SZ; ++l) {
        const float4* hv4 = reinterpret_cast<const float4*>(&hs[cur][0]);
        float a0 = 0.0f, a1 = 0.0f, a2 = 0.0f, a3 = 0.0f;   // 4 chains for ILP
        #pragma unroll
        for (int j = 0; j < H_SZ / 4; j += 4) {
            a0 += dot4(wreg[j    ], hv4[j    ]);
            a1 += dot4(wreg[j + 1], hv4[j + 1]);
            a2 += dot4(wreg[j + 2], hv4[j + 2]);
            a3 += dot4(wreg[j + 3], hv4[j + 3]);
        }
        gh_s[t] = bhh + ((a0 + a1) + (a2 + a3));
        __syncthreads();                       // [A] gh_s visible

        if (t < H_SZ) {
            const float r = sigmoidf(gi_all[l][t]           + gh_s[t]);
            const float z = sigmoidf(gi_all[l][t +   H_SZ]  + gh_s[t +   H_SZ]);
            const float n = tanhf  (gi_all[l][t + 2*H_SZ]  + r * gh_s[t + 2*H_SZ]);
            hnew = (1.0f - z) * n + z * hs[cur][t];
            hs[cur ^ 1][t] = hnew;
        }
        __syncthreads();                       // [B] hs[cur^1] visible
        cur ^= 1;
    }

    if (t < H_SZ) enc[(size_t)b * H_SZ + t] = hnew;
}

// Single wave: lane j handles enc row 1+j (10 pos + 50 neg = 60 rows)
__global__ __launch_bounds__(64) void loss_kernel(
    const float* __restrict__ enc,   // [B][H]
    float* __restrict__ out)         // f32 scalar (reference output dtype)
{
    __shared__ float node[H_SZ];
    const int t = threadIdx.x;
    node[t]      = enc[t];
    node[t + 64] = enc[t + 64];
    __syncthreads();

    float vp = 0.0f, vn = 0.0f;
    if (t < P_SZ + N_SZ) {
        const float4* row4 = reinterpret_cast<const float4*>(enc + (size_t)(1 + t) * H_SZ);
        float s = 0.0f;
        #pragma unroll 8
        for (int i4 = 0; i4 < H_SZ / 4; ++i4) {
            s += dot4(reinterpret_cast<const float4*>(node)[i4], row4[i4]);
        }
        s *= (1.0f / (float)H_SZ);
        if (t < P_SZ) vp = s;                               // pos dot
        else          vn = (s > 0.0f) ? expf(s) : 0.0f;     // exp(s)*(s>0)
    }

    #pragma unroll
    for (int off = 32; off > 0; off >>= 1) {
        vp += __shfl_down(vp, off);
        vn += __shfl_down(vn, off);
    }
    if (t == 0) {
        out[0] = logf(1.0f + vn) - vp;   // -(neg_loss + pos_loss)
    }
}

extern "C" void kernel_launch(void* const* d_in, const int* in_sizes, int n_in,
                              void* d_out, int out_size, void* d_ws, size_t ws_size,
                              hipStream_t stream) {
    const int*   phr_inds = (const int*)  d_in[0];
    const int*   pos_inds = (const int*)  d_in[1];
    const int*   neg_inds = (const int*)  d_in[2];
    const float* u_emb    = (const float*)d_in[3];
    const float* v_emb    = (const float*)d_in[4];
    const float* w_ih     = (const float*)d_in[5];
    const float* w_hh     = (const float*)d_in[6];
    const float* b_ih     = (const float*)d_in[7];
    const float* b_hh     = (const float*)d_in[8];
    const float* h0       = (const float*)d_in[9];

    float* enc = (float*)d_ws;   // [B][H] = 61*128 floats

    gru_encode<<<B_SZ, G_SZ, 0, stream>>>(phr_inds, pos_inds, neg_inds,
                                          u_emb, v_emb, w_ih, w_hh, b_ih, b_hh, h0,
                                          enc);
    loss_kernel<<<1, 64, 0, stream>>>(enc, (float*)d_out);
}